// Round 8
// baseline (404.772 us; speedup 1.0000x reference)
//
#include <hip/hip_runtime.h>
#include <hip/hip_bf16.h>
#include <hip/hip_fp16.h>

#define NEG_SLOPE 0.2f
#define BCAP 12288      // fixed bucket capacity per 512 nodes (mean 8163, 45-sigma slack)

__device__ __forceinline__ float lrelu(float v) { return v >= 0.f ? v : NEG_SLOPE * v; }

__device__ __forceinline__ float wave_sum(float v) {
    for (int o = 32; o; o >>= 1) v += __shfl_down(v, o, 64);
    return v;
}

__device__ __forceinline__ void h8_to_f(const uint4 v, float* f) {
    float2 a = __half22float2(*(const __half2*)&v.x);
    float2 b = __half22float2(*(const __half2*)&v.y);
    float2 c = __half22float2(*(const __half2*)&v.z);
    float2 d = __half22float2(*(const __half2*)&v.w);
    f[0] = a.x; f[1] = a.y; f[2] = b.x; f[3] = b.y;
    f[4] = c.x; f[5] = c.y; f[6] = d.x; f[7] = d.y;
}

// ce1[h] = dot(We1[h*64..], ae1[h*64..]) — wave h computes head h. 256 threads.
__device__ __forceinline__ void compute_ce1(const float* __restrict__ We1,
                                            const float* __restrict__ ae1,
                                            float* ce /*shared[4]*/) {
    int t = threadIdx.x;
    float p = wave_sum(We1[t] * ae1[t]);
    if ((t & 63) == 0) ce[t >> 6] = p;
    __syncthreads();
}

__device__ __forceinline__ float compute_ce2(const float* __restrict__ We2,
                                             const float* __restrict__ ae2,
                                             float* sh /*shared[1]*/) {
    int t = threadIdx.x;
    if (t < 64) {
        float p = wave_sum(We2[t] * ae2[t]);
        if (t == 0) sh[0] = p;
    }
    __syncthreads();
    return sh[0];
}

// ---------------- Layer-1 prep: al_s1/al_d1; zero deg; block 0 computes folded V -----
// V layout (global): [0..255]=V0W, [256..511]=V1W, [512..575]=cW, [576..639]=cb2,
// [640..643]=V0.as2, [644..647]=V1.as2, [648..651]=V0.ad2, [652..655]=V1.ad2,
// [656]=c.as2, [657]=c.ad2   (all Wr1/b2/c pushed through the linear tail)
__global__ __launch_bounds__(256) void prep1_kernel(
    const float* __restrict__ x, const float* __restrict__ W1,
    const float* __restrict__ as1, const float* __restrict__ ad1,
    const float* __restrict__ W2, const float* __restrict__ b1,
    const float* __restrict__ Wr1, const float* __restrict__ b2,
    const float* __restrict__ as2, const float* __restrict__ ad2,
    float* __restrict__ al_s1, float* __restrict__ al_d1,
    int* __restrict__ deg, float* __restrict__ V, int N) {
    __shared__ float cs0[4], cs1[4], cd0[4], cd1[4];
    __shared__ float sV0[256], sV1[256], sc[64];
    int t = threadIdx.x;
    {
        float a = as1[t], d = ad1[t], u0 = W1[t], u1 = W1[256 + t];
        float p0 = wave_sum(u0 * a);
        float p1 = wave_sum(u1 * a);
        float q0 = wave_sum(u0 * d);
        float q1 = wave_sum(u1 * d);
        if ((t & 63) == 0) {
            int h = t >> 6;
            cs0[h] = p0; cs1[h] = p1; cd0[h] = q0; cd1[h] = q1;
        }
    }
    __syncthreads();
    int n = blockIdx.x * 256 + t;
    if (n < N) {
        deg[n] = 0;
        float2 xs = ((const float2*)x)[n];
        float4 vs, vd;
        vs.x = xs.x * cs0[0] + xs.y * cs1[0];
        vs.y = xs.x * cs0[1] + xs.y * cs1[1];
        vs.z = xs.x * cs0[2] + xs.y * cs1[2];
        vs.w = xs.x * cs0[3] + xs.y * cs1[3];
        vd.x = xs.x * cd0[0] + xs.y * cd1[0];
        vd.y = xs.x * cd0[1] + xs.y * cd1[1];
        vd.z = xs.x * cd0[2] + xs.y * cd1[2];
        vd.w = xs.x * cd0[3] + xs.y * cd1[3];
        ((float4*)al_s1)[n] = vs;
        ((float4*)al_d1)[n] = vd;
    }
    // block 0 epilogue: fold W1@W2 (=V0,V1), b1@W2 (=c), then push Wr1/as2/ad2 through
    if (blockIdx.x == 0) {
        int h = t >> 6, j = t & 63;
        float v0 = 0.f, v1 = 0.f;
        for (int k = 0; k < 64; ++k) {
            float w2 = W2[(h * 64 + k) * 64 + j];
            v0 += W1[h * 64 + k] * w2;
            v1 += W1[256 + h * 64 + k] * w2;
        }
        sV0[t] = v0;
        sV1[t] = v1;
        if (t < 64) {
            float c = 0.f;
            for (int i = 0; i < 256; ++i) c += b1[i] * W2[i * 64 + t];
            sc[t] = c;
        }
        __syncthreads();
        float v0w = 0.f, v1w = 0.f;
        for (int k = 0; k < 64; ++k) {
            float wr = Wr1[k * 64 + j];
            v0w += sV0[h * 64 + k] * wr;
            v1w += sV1[h * 64 + k] * wr;
        }
        V[t] = v0w;
        V[256 + t] = v1w;
        if (t < 64) {
            float cw = 0.f, cb = 0.f;
            for (int k = 0; k < 64; ++k) {
                float wr = Wr1[k * 64 + t];
                cw += sc[k] * wr;
                cb += b2[k] * wr;
            }
            V[512 + t] = cw;
            V[576 + t] = cb;
        }
        int lane = t & 63;
        float p0 = wave_sum(sV0[t] * as2[lane]);
        float p1 = wave_sum(sV1[t] * as2[lane]);
        float q0 = wave_sum(sV0[t] * ad2[lane]);
        float q1 = wave_sum(sV1[t] * ad2[lane]);
        if (lane == 0) {
            V[640 + h] = p0; V[644 + h] = p1; V[648 + h] = q0; V[652 + h] = q1;
        }
        if (t < 64) {
            float r0 = wave_sum(sc[t] * as2[t]);
            float r1 = wave_sum(sc[t] * ad2[t]);
            if (t == 0) { V[656] = r0; V[657] = r1; }
        }
    }
}

// ---------------- CSR build pass 1: degree histogram via direct global atomics -------
// E atomics spread over N addresses (~16 contenders each) — throughput-bound, no
// staging buffer, no LDS serialization. Replaces the old binA/ebm machinery.
__global__ __launch_bounds__(256) void hist_kernel(
    const int* __restrict__ ei, int* __restrict__ deg, int E) {
    int stride = gridDim.x * 256;
    for (int e = blockIdx.x * 256 + threadIdx.x; e < E; e += stride)
        atomicAdd(&deg[ei[E + e]], 1);
}

// ---------------- CSR build pass 2: per-512-node-bucket scan of deg ------------------
// Exact packing within each fixed-capacity BCAP region; writes offs (segment END) and
// cur (segment start = fill pointer for pass 3). ~0.4MB reads, trivial cost.
__global__ __launch_bounds__(256) void scan_kernel(
    const int* __restrict__ deg, int* __restrict__ offs, int* __restrict__ cur, int N) {
    __shared__ int psum[256];
    int b = blockIdx.x, n0 = b << 9, t = threadIdx.x;
    int na = n0 + 2 * t, nb = na + 1;
    int a0 = (na < N) ? deg[na] : 0;
    int a1 = (nb < N) ? deg[nb] : 0;
    psum[t] = a0 + a1;
    __syncthreads();
    for (int o = 1; o < 256; o <<= 1) {
        int a = (t >= o) ? psum[t - o] : 0;
        __syncthreads();
        psum[t] += a;
        __syncthreads();
    }
    int excl = psum[t] - (a0 + a1);
    int bstart = b * BCAP;
    if (na < N) { cur[na] = bstart + excl;      offs[na] = bstart + excl + a0; }
    if (nb < N) { cur[nb] = bstart + excl + a0; offs[nb] = bstart + excl + a0 + a1; }
}

// ---------------- CSR build pass 3: direct scatter via per-node fill pointers --------
// Coalesced reads of src/dst/ea; one global atomic + one 4B scattered store per edge.
// Segment-internal order is arbitrary (all consumers are order-invariant sums).
__global__ __launch_bounds__(256) void scat_kernel(
    const int* __restrict__ ei, const float* __restrict__ ea,
    int* __restrict__ cur, unsigned* __restrict__ csr_se, int E) {
    int stride = gridDim.x * 256;
    for (int e = blockIdx.x * 256 + threadIdx.x; e < E; e += stride) {
        int d = ei[E + e];
        unsigned q = (unsigned)(ea[e] * 32767.f + 0.5f);
        q = min(q, 32767u);
        int pos = atomicAdd(&cur[d], 1);
        csr_se[pos] = (((unsigned)ei[e]) << 15) | q;
    }
}

// ---------------- Layer-1 aggregation + layer-2 logit scalars --------------------------
// Rank-2 softmax-weighted x aggregation per (node,head); then al_s2/al_d2 from the 18
// folded scalars via a 4-lane shuffle reduce.
__global__ __launch_bounds__(256) void aggX_kernel(
    const unsigned* __restrict__ csr_se, const int* __restrict__ offs,
    const int* __restrict__ deg,
    const float* __restrict__ al_s1, const float* __restrict__ al_d1,
    const float* __restrict__ x,
    const float* __restrict__ We1, const float* __restrict__ ae1,
    const float* __restrict__ V,
    float2* __restrict__ XA, float* __restrict__ al_s2, float* __restrict__ al_d2,
    int N) {
    __shared__ float ce[4];
    __shared__ float sS[18];
    if (threadIdx.x < 18) sS[threadIdx.x] = V[640 + threadIdx.x];
    compute_ce1(We1, ae1, ce);
    int t = blockIdx.x * 256 + threadIdx.x;
    int n = t >> 2, h = t & 3;
    if (n >= N) return;
    int dc = deg[n];
    int start = offs[n] - dc;
    float ald = al_d1[4 * n + h];
    float ceh = ce[h] * (1.f / 32767.f);
    const float2* x2 = (const float2*)x;
    float z = 0.f, X0 = 0.f, X1 = 0.f;
    int j = 0;
    for (; j + 2 <= dc; j += 2) {
        unsigned w0 = csr_se[start + j];
        unsigned w1 = csr_se[start + j + 1];
        int s0 = w0 >> 15, s1 = w1 >> 15;
        float als0 = al_s1[4 * s0 + h];
        float als1 = al_s1[4 * s1 + h];
        float2 xs0 = x2[s0];
        float2 xs1 = x2[s1];
        float e0 = __expf(lrelu(als0 + ald + (float)(w0 & 32767u) * ceh));
        float e1 = __expf(lrelu(als1 + ald + (float)(w1 & 32767u) * ceh));
        z += e0 + e1;
        X0 += e0 * xs0.x + e1 * xs1.x;
        X1 += e0 * xs0.y + e1 * xs1.y;
    }
    if (j < dc) {
        unsigned w = csr_se[start + j];
        int s = w >> 15;
        float als = al_s1[4 * s + h];
        float2 xs = x2[s];
        float ex = __expf(lrelu(als + ald + (float)(w & 32767u) * ceh));
        z += ex;
        X0 += ex * xs.x;
        X1 += ex * xs.y;
    }
    float inv = 1.f / (z + 1e-16f);
    float xa0 = X0 * inv, xa1 = X1 * inv;
    XA[(size_t)4 * n + h] = make_float2(xa0, xa1);
    // al_s2/al_d2: reduce per-head partials over the 4-lane group
    float ps = xa0 * sS[h] + xa1 * sS[4 + h];
    float pd = xa0 * sS[8 + h] + xa1 * sS[12 + h];
    ps += __shfl_xor(ps, 1, 64); ps += __shfl_xor(ps, 2, 64);
    pd += __shfl_xor(pd, 1, 64); pd += __shfl_xor(pd, 2, 64);
    if (h == 0) {
        al_s2[n] = sS[16] + ps;
        al_d2[n] = sS[17] + pd;
    }
}

// ---------------- Layer-2 rank-8 aggregation -> packed fp16 (Y[8]) + w0 per node -----
// One lane per edge; 32B XA gathers (L2-resident 3.2MB table); exp once per edge.
// Output is the 9-dim compressed node state the edge regressor expands from.
__global__ __launch_bounds__(256) void msg2y_kernel(
    const unsigned* __restrict__ csr_se, const int* __restrict__ offs,
    const int* __restrict__ deg,
    const float* __restrict__ al_s2, const float* __restrict__ al_d2,
    const float* __restrict__ We2, const float* __restrict__ ae2,
    const float2* __restrict__ XA,
    uint4* __restrict__ Yh, float* __restrict__ w0n, int N) {
    __shared__ float sh[1];
    float ce2 = compute_ce2(We2, ae2, sh) * (1.f / 32767.f);
    int t = blockIdx.x * 256 + threadIdx.x;
    int n = t >> 2, q = t & 3;
    if (n >= N) return;
    int dc = deg[n];
    int start = offs[n] - dc;
    float ald = al_d2[n];
    const float4* xa4 = (const float4*)XA;   // node s -> xa4[2s], xa4[2s+1]
    float y0 = 0.f, y1 = 0.f, y2 = 0.f, y3 = 0.f;
    float y4 = 0.f, y5 = 0.f, y6 = 0.f, y7 = 0.f;
    float z = 0.f;
    int j = q;
    for (; j + 4 < dc; j += 8) {
        unsigned wA = csr_se[start + j];
        unsigned wB = csr_se[start + j + 4];
        int sA = wA >> 15, sB = wB >> 15;
        float alsA = al_s2[sA];
        float alsB = al_s2[sB];
        float4 a0 = xa4[(size_t)sA * 2];
        float4 a1 = xa4[(size_t)sA * 2 + 1];
        float4 b0 = xa4[(size_t)sB * 2];
        float4 b1 = xa4[(size_t)sB * 2 + 1];
        float exA = __expf(lrelu(alsA + ald + (float)(wA & 32767u) * ce2));
        float exB = __expf(lrelu(alsB + ald + (float)(wB & 32767u) * ce2));
        z += exA + exB;
        y0 += exA * a0.x + exB * b0.x;
        y1 += exA * a0.y + exB * b0.y;
        y2 += exA * a0.z + exB * b0.z;
        y3 += exA * a0.w + exB * b0.w;
        y4 += exA * a1.x + exB * b1.x;
        y5 += exA * a1.y + exB * b1.y;
        y6 += exA * a1.z + exB * b1.z;
        y7 += exA * a1.w + exB * b1.w;
    }
    if (j < dc) {
        unsigned w = csr_se[start + j];
        int s = w >> 15;
        float als = al_s2[s];
        float4 a0 = xa4[(size_t)s * 2];
        float4 a1 = xa4[(size_t)s * 2 + 1];
        float ex = __expf(lrelu(als + ald + (float)(w & 32767u) * ce2));
        z += ex;
        y0 += ex * a0.x; y1 += ex * a0.y; y2 += ex * a0.z; y3 += ex * a0.w;
        y4 += ex * a1.x; y5 += ex * a1.y; y6 += ex * a1.z; y7 += ex * a1.w;
    }
    // reduce 9 accumulators across the 4-lane group (xor butterfly -> all lanes full)
    y0 += __shfl_xor(y0, 1, 64); y0 += __shfl_xor(y0, 2, 64);
    y1 += __shfl_xor(y1, 1, 64); y1 += __shfl_xor(y1, 2, 64);
    y2 += __shfl_xor(y2, 1, 64); y2 += __shfl_xor(y2, 2, 64);
    y3 += __shfl_xor(y3, 1, 64); y3 += __shfl_xor(y3, 2, 64);
    y4 += __shfl_xor(y4, 1, 64); y4 += __shfl_xor(y4, 2, 64);
    y5 += __shfl_xor(y5, 1, 64); y5 += __shfl_xor(y5, 2, 64);
    y6 += __shfl_xor(y6, 1, 64); y6 += __shfl_xor(y6, 2, 64);
    y7 += __shfl_xor(y7, 1, 64); y7 += __shfl_xor(y7, 2, 64);
    z += __shfl_xor(z, 1, 64); z += __shfl_xor(z, 2, 64);
    if (q == 0) {
        float inv = 1.f / (z + 1e-16f);
        __half2 p0 = __floats2half2_rn(y0 * inv, y1 * inv);
        __half2 p1 = __floats2half2_rn(y2 * inv, y3 * inv);
        __half2 p2 = __floats2half2_rn(y4 * inv, y5 * inv);
        __half2 p3 = __floats2half2_rn(y6 * inv, y7 * inv);
        uint4 o;
        o.x = *(unsigned*)&p0; o.y = *(unsigned*)&p1;
        o.z = *(unsigned*)&p2; o.w = *(unsigned*)&p3;
        Yh[n] = o;
        w0n[n] = z * inv;   // ~1, or 0 for empty segments (kills cW term)
    }
}

// ---------------- Edge regressor: ONE THREAD PER EDGE, scalar-operand basis -----------
// The 9x64 basis (V) is wave-uniform: the unrolled k-loop reads compile-time offsets of
// V/br1/Wr2 -> s_loads feeding VALU as SGPR operands. Each thread owns one edge:
// 2 coalesced ei loads, 2x16B Yh gathers (1.6MB L2-resident), 2 w0 loads, then
// 64 dims x (9 FMA + max + FMA) with zero cross-lane redundancy.
__global__ __launch_bounds__(256) void edge_kernel(
    const int* __restrict__ ei,
    const uint4* __restrict__ Yh, const float* __restrict__ w0n,
    const float* __restrict__ V,
    const float* __restrict__ br1, const float* __restrict__ Wr2,
    const float* __restrict__ br2, float* __restrict__ out, int E) {
    int e = blockIdx.x * 256 + threadIdx.x;
    if (e >= E) return;
    int s = ei[e], d = ei[E + e];
    uint4 ys = Yh[s], yd = Yh[d];
    float w0 = w0n[s] + w0n[d];
    float fs[8], fd[8], tt[8];
    h8_to_f(ys, fs);
    h8_to_f(yd, fd);
#pragma unroll
    for (int i = 0; i < 8; ++i) tt[i] = fs[i] + fd[i];
    float acc = 0.f;
#pragma unroll
    for (int k = 0; k < 64; ++k) {
        float g = fmaf(w0, V[512 + k], fmaf(2.f, V[576 + k], br1[k]));
        g = fmaf(tt[0], V[k],       g);
        g = fmaf(tt[1], V[256 + k], g);
        g = fmaf(tt[2], V[64 + k],  g);
        g = fmaf(tt[3], V[320 + k], g);
        g = fmaf(tt[4], V[128 + k], g);
        g = fmaf(tt[5], V[384 + k], g);
        g = fmaf(tt[6], V[192 + k], g);
        g = fmaf(tt[7], V[448 + k], g);
        acc = fmaf(fmaxf(g, 0.f), Wr2[k], acc);
    }
    out[e] = acc + br2[0];
}

extern "C" void kernel_launch(void* const* d_in, const int* in_sizes, int n_in,
                              void* d_out, int out_size, void* d_ws, size_t ws_size,
                              hipStream_t stream) {
    const float* x    = (const float*)d_in[0];
    const int*   ei   = (const int*)d_in[1];
    const float* ea   = (const float*)d_in[2];
    const float* W1   = (const float*)d_in[3];
    const float* We1  = (const float*)d_in[4];
    const float* as1  = (const float*)d_in[5];
    const float* ad1  = (const float*)d_in[6];
    const float* ae1  = (const float*)d_in[7];
    const float* b1   = (const float*)d_in[8];
    const float* W2   = (const float*)d_in[9];
    const float* We2  = (const float*)d_in[10];
    const float* as2  = (const float*)d_in[11];
    const float* ad2  = (const float*)d_in[12];
    const float* ae2  = (const float*)d_in[13];
    const float* b2   = (const float*)d_in[14];
    const float* Wr1  = (const float*)d_in[15];
    const float* br1  = (const float*)d_in[16];
    const float* Wr2  = (const float*)d_in[17];
    const float* br2  = (const float*)d_in[18];
    float* out = (float*)d_out;

    const int N = in_sizes[0] / 2;
    const int E = in_sizes[2];
    const int nbuck = (N + 511) >> 9;
    const size_t capE = (size_t)nbuck * BCAP;   // fixed-capacity CSR address space

    // workspace layout
    float* ws = (float*)d_ws;
    float*    al_s1 = ws;                            // N*4
    float*    al_d1 = al_s1 + (size_t)N * 4;         // N*4
    float*    al_s2 = al_d1 + (size_t)N * 4;         // N
    float*    al_d2 = al_s2 + N;                     // N
    float2*   XA    = (float2*)((((uintptr_t)(al_d2 + N)) + 31) & ~(uintptr_t)31); // N*4 float2 (32B aligned)
    float*    V     = (float*)((((uintptr_t)(XA + (size_t)N * 4)) + 15) & ~(uintptr_t)15); // 658 (pad 704)
    int*      deg   = (int*)(V + 704);               // N
    int*      offs  = deg + N;                       // N
    int*      cur   = offs + N;                      // N (fill pointers)
    uint4*    Yh    = (uint4*)((((uintptr_t)(cur + N)) + 15) & ~(uintptr_t)15); // N uint4
    float*    w0n   = (float*)(Yh + N);              // N
    unsigned* csr_se = (unsigned*)((((uintptr_t)(w0n + N)) + 15) & ~(uintptr_t)15); // capE

    const int nb = (N + 255) / 256;

    prep1_kernel<<<nb, 256, 0, stream>>>(x, W1, as1, ad1, W2, b1, Wr1, b2, as2, ad2,
                                         al_s1, al_d1, deg, V, N);
    hist_kernel<<<1024, 256, 0, stream>>>(ei, deg, E);
    scan_kernel<<<nbuck, 256, 0, stream>>>(deg, offs, cur, N);
    scat_kernel<<<2048, 256, 0, stream>>>(ei, ea, cur, csr_se, E);
    aggX_kernel<<<(4 * N + 255) / 256, 256, 0, stream>>>(csr_se, offs, deg,
                                                         al_s1, al_d1, x, We1, ae1, V,
                                                         XA, al_s2, al_d2, N);
    msg2y_kernel<<<(4 * N + 255) / 256, 256, 0, stream>>>(csr_se, offs, deg,
                                                          al_s2, al_d2, We2, ae2, XA,
                                                          Yh, w0n, N);
    edge_kernel<<<(E + 255) / 256, 256, 0, stream>>>(ei, Yh, w0n, V, br1, Wr2, br2,
                                                     out, E);
}

// Round 9
// 241.752 us; speedup vs baseline: 1.6743x; 1.6743x over previous
//
#include <hip/hip_runtime.h>
#include <hip/hip_bf16.h>
#include <hip/hip_fp16.h>

#define NEG_SLOPE 0.2f
#define NBUCK_MAX 256   // buckets of 512 nodes; 100k nodes -> 196 buckets
#define BCAP 12288      // fixed bucket capacity (mean 8163, sigma ~90 -> 45 sigma slack)
#define TILE 2048       // edges per binA block (8 per thread)

__device__ __forceinline__ float lrelu(float v) { return v >= 0.f ? v : NEG_SLOPE * v; }

__device__ __forceinline__ float wave_sum(float v) {
    for (int o = 32; o; o >>= 1) v += __shfl_down(v, o, 64);
    return v;
}

__device__ __forceinline__ void h8_to_f(const uint4 v, float* f) {
    float2 a = __half22float2(*(const __half2*)&v.x);
    float2 b = __half22float2(*(const __half2*)&v.y);
    float2 c = __half22float2(*(const __half2*)&v.z);
    float2 d = __half22float2(*(const __half2*)&v.w);
    f[0] = a.x; f[1] = a.y; f[2] = b.x; f[3] = b.y;
    f[4] = c.x; f[5] = c.y; f[6] = d.x; f[7] = d.y;
}

// ce1[h] = dot(We1[h*64..], ae1[h*64..]) — wave h computes head h. 256 threads.
__device__ __forceinline__ void compute_ce1(const float* __restrict__ We1,
                                            const float* __restrict__ ae1,
                                            float* ce /*shared[4]*/) {
    int t = threadIdx.x;
    float p = wave_sum(We1[t] * ae1[t]);
    if ((t & 63) == 0) ce[t >> 6] = p;
    __syncthreads();
}

__device__ __forceinline__ float compute_ce2(const float* __restrict__ We2,
                                             const float* __restrict__ ae2,
                                             float* sh /*shared[1]*/) {
    int t = threadIdx.x;
    if (t < 64) {
        float p = wave_sum(We2[t] * ae2[t]);
        if (t == 0) sh[0] = p;
    }
    __syncthreads();
    return sh[0];
}

// ---------------- Layer-1 prep: al_s1/al_d1; init bucket_cur; block 0 folds V --------
// V layout (global): [0..255]=V0W, [256..511]=V1W, [512..575]=cW, [576..639]=cb2,
// [640..643]=V0.as2, [644..647]=V1.as2, [648..651]=V0.ad2, [652..655]=V1.ad2,
// [656]=c.as2, [657]=c.ad2   (all Wr1/b2/c pushed through the linear tail)
__global__ __launch_bounds__(256) void prep1_kernel(
    const float* __restrict__ x, const float* __restrict__ W1,
    const float* __restrict__ as1, const float* __restrict__ ad1,
    const float* __restrict__ W2, const float* __restrict__ b1,
    const float* __restrict__ Wr1, const float* __restrict__ b2,
    const float* __restrict__ as2, const float* __restrict__ ad2,
    float* __restrict__ al_s1, float* __restrict__ al_d1,
    int* __restrict__ bucket_cur, float* __restrict__ V, int N) {
    __shared__ float cs0[4], cs1[4], cd0[4], cd1[4];
    __shared__ float sV0[256], sV1[256], sc[64];
    int t = threadIdx.x;
    if (blockIdx.x == 0) bucket_cur[t] = t * BCAP;
    {
        float a = as1[t], d = ad1[t], u0 = W1[t], u1 = W1[256 + t];
        float p0 = wave_sum(u0 * a);
        float p1 = wave_sum(u1 * a);
        float q0 = wave_sum(u0 * d);
        float q1 = wave_sum(u1 * d);
        if ((t & 63) == 0) {
            int h = t >> 6;
            cs0[h] = p0; cs1[h] = p1; cd0[h] = q0; cd1[h] = q1;
        }
    }
    __syncthreads();
    int n = blockIdx.x * 256 + t;
    if (n < N) {
        float2 xs = ((const float2*)x)[n];
        float4 vs, vd;
        vs.x = xs.x * cs0[0] + xs.y * cs1[0];
        vs.y = xs.x * cs0[1] + xs.y * cs1[1];
        vs.z = xs.x * cs0[2] + xs.y * cs1[2];
        vs.w = xs.x * cs0[3] + xs.y * cs1[3];
        vd.x = xs.x * cd0[0] + xs.y * cd1[0];
        vd.y = xs.x * cd0[1] + xs.y * cd1[1];
        vd.z = xs.x * cd0[2] + xs.y * cd1[2];
        vd.w = xs.x * cd0[3] + xs.y * cd1[3];
        ((float4*)al_s1)[n] = vs;
        ((float4*)al_d1)[n] = vd;
    }
    // block 0 epilogue: fold W1@W2 (=V0,V1), b1@W2 (=c), then push Wr1/as2/ad2 through
    if (blockIdx.x == 0) {
        int h = t >> 6, j = t & 63;
        float v0 = 0.f, v1 = 0.f;
        for (int k = 0; k < 64; ++k) {
            float w2 = W2[(h * 64 + k) * 64 + j];
            v0 += W1[h * 64 + k] * w2;
            v1 += W1[256 + h * 64 + k] * w2;
        }
        sV0[t] = v0;
        sV1[t] = v1;
        if (t < 64) {
            float c = 0.f;
            for (int i = 0; i < 256; ++i) c += b1[i] * W2[i * 64 + t];
            sc[t] = c;
        }
        __syncthreads();
        float v0w = 0.f, v1w = 0.f;
        for (int k = 0; k < 64; ++k) {
            float wr = Wr1[k * 64 + j];
            v0w += sV0[h * 64 + k] * wr;
            v1w += sV1[h * 64 + k] * wr;
        }
        V[t] = v0w;
        V[256 + t] = v1w;
        if (t < 64) {
            float cw = 0.f, cb = 0.f;
            for (int k = 0; k < 64; ++k) {
                float wr = Wr1[k * 64 + t];
                cw += sc[k] * wr;
                cb += b2[k] * wr;
            }
            V[512 + t] = cw;
            V[576 + t] = cb;
        }
        int lane = t & 63;
        float p0 = wave_sum(sV0[t] * as2[lane]);
        float p1 = wave_sum(sV1[t] * as2[lane]);
        float q0 = wave_sum(sV0[t] * ad2[lane]);
        float q1 = wave_sum(sV1[t] * ad2[lane]);
        if (lane == 0) {
            V[640 + h] = p0; V[644 + h] = p1; V[648 + h] = q0; V[652 + h] = q1;
        }
        if (t < 64) {
            float r0 = wave_sum(sc[t] * as2[t]);
            float r1 = wave_sum(sc[t] * ad2[t]);
            if (t == 0) { V[656] = r0; V[657] = r1; }
        }
    }
}

// ---------------- Pass A: tile-sorted binning (single pass over edges) ----------------
// One block per 2048-edge tile. Rank edges per bucket with LDS atomics, block-scan the
// bucket counts, reserve global space with <=196 block-level atomics (never per-edge),
// reorder records bucket-contiguously in LDS, then write out in position order:
// runs of ~10 consecutive ebm slots per bucket -> near-coalesced 8B stores (vs fully
// scattered stores = 2.7x write amplification + store-queue stalls in the old binA).
// ebm.x = (src<<15) | ea15 ; ebm.y = (dst_local<<21) | eid
__global__ __launch_bounds__(256) void binA_kernel(
    const int* __restrict__ ei, const float* __restrict__ ea,
    int* __restrict__ bucket_cur, uint2* __restrict__ ebm, int E, int nbuck) {
    __shared__ int cnt[NBUCK_MAX];
    __shared__ int gbase[NBUCK_MAX];
    __shared__ int lofs[NBUCK_MAX];
    __shared__ int psum[NBUCK_MAX];
    __shared__ uint2 buf[TILE];
    __shared__ unsigned short bkt[TILE];
    int t = threadIdx.x;
    int e0 = blockIdx.x * TILE;
    int cntE = min(TILE, E - e0);
    for (int i = t; i < nbuck; i += 256) cnt[i] = 0;
    __syncthreads();
    uint2 rec[8];
    int rb[8], rr[8];
#pragma unroll
    for (int i = 0; i < 8; ++i) {
        int e = e0 + i * 256 + t;
        if (i * 256 + t < cntE) {
            int s = ei[e], d = ei[E + e];
            unsigned q = (unsigned)(ea[e] * 32767.f + 0.5f);
            q = min(q, 32767u);
            rec[i] = make_uint2((((unsigned)s) << 15) | q,
                                (unsigned)(((d & 511) << 21) | e));
            rb[i] = d >> 9;
            rr[i] = atomicAdd(&cnt[rb[i]], 1);
        } else {
            rb[i] = -1;
        }
    }
    __syncthreads();
    // exclusive scan of cnt over [0, nbuck) + global reservation (one atomic/bucket)
    int v = (t < nbuck) ? cnt[t] : 0;
    psum[t] = v;
    __syncthreads();
    for (int o = 1; o < 256; o <<= 1) {
        int a = (t >= o) ? psum[t - o] : 0;
        __syncthreads();
        psum[t] += a;
        __syncthreads();
    }
    if (t < nbuck) {
        lofs[t] = psum[t] - v;
        if (v) gbase[t] = atomicAdd(&bucket_cur[t], v);
    }
    __syncthreads();
    // scatter into LDS, bucket-contiguous
#pragma unroll
    for (int i = 0; i < 8; ++i) {
        if (rb[i] >= 0) {
            int p = lofs[rb[i]] + rr[i];
            buf[p] = rec[i];
            bkt[p] = (unsigned short)rb[i];
        }
    }
    __syncthreads();
    // write out: consecutive p -> consecutive slots within each bucket's run
    for (int p = t; p < cntE; p += 256) {
        int b = bkt[p];
        ebm[gbase[b] + (p - lofs[b])] = buf[p];
    }
}

// ---------------- Pass B: per bucket — LDS deg-histogram, local scan, exact scatter ----
__global__ __launch_bounds__(256) void binB_kernel(
    const uint2* __restrict__ ebm, const int* __restrict__ bucket_cur,
    int* __restrict__ deg, int* __restrict__ offs,
    unsigned* __restrict__ csr_se, int N) {
    __shared__ int lcnt[512];
    __shared__ int lofs[512];
    __shared__ int lcur[512];
    int b = blockIdx.x;
    int n0 = b << 9;
    int t = threadIdx.x;
    lcnt[t] = 0; lcnt[t + 256] = 0;
    __syncthreads();
    int bstart = b * BCAP;
    int bend = bucket_cur[b];      // post-binA == region fill end
    for (int p = bstart + t; p < bend; p += 256)
        atomicAdd(&lcnt[ebm[p].y >> 21], 1);
    __syncthreads();
    int a0 = lcnt[2 * t], a1 = lcnt[2 * t + 1];
    __shared__ int psum[256];
    psum[t] = a0 + a1;
    __syncthreads();
    for (int o = 1; o < 256; o <<= 1) {
        int a = (t >= o) ? psum[t - o] : 0;
        __syncthreads();
        psum[t] += a;
        __syncthreads();
    }
    int excl = psum[t] - (a0 + a1);
    lofs[2 * t] = excl;
    lofs[2 * t + 1] = excl + a0;
    lcur[2 * t] = bstart + excl;
    lcur[2 * t + 1] = bstart + excl + a0;
    __syncthreads();
    for (int i = t; i < 512; i += 256) {
        int n = n0 + i;
        if (n < N) {
            deg[n] = lcnt[i];
            offs[n] = bstart + lofs[i] + lcnt[i];   // segment END (fixed address space)
        }
    }
    for (int p = bstart + t; p < bend; p += 256) {
        uint2 m = ebm[p];
        int pos = atomicAdd(&lcur[m.y >> 21], 1);
        csr_se[pos] = m.x;
    }
}

// ---------------- Layer-1 aggregation + layer-2 logit scalars --------------------------
// Rank-2 softmax-weighted x aggregation per (node,head); then al_s2/al_d2 from the 18
// folded scalars via a 4-lane shuffle reduce.
__global__ __launch_bounds__(256) void aggX_kernel(
    const unsigned* __restrict__ csr_se, const int* __restrict__ offs,
    const int* __restrict__ deg,
    const float* __restrict__ al_s1, const float* __restrict__ al_d1,
    const float* __restrict__ x,
    const float* __restrict__ We1, const float* __restrict__ ae1,
    const float* __restrict__ V,
    float2* __restrict__ XA, float* __restrict__ al_s2, float* __restrict__ al_d2,
    int N) {
    __shared__ float ce[4];
    __shared__ float sS[18];
    if (threadIdx.x < 18) sS[threadIdx.x] = V[640 + threadIdx.x];
    compute_ce1(We1, ae1, ce);
    int t = blockIdx.x * 256 + threadIdx.x;
    int n = t >> 2, h = t & 3;
    if (n >= N) return;
    int dc = deg[n];
    int start = offs[n] - dc;
    float ald = al_d1[4 * n + h];
    float ceh = ce[h] * (1.f / 32767.f);
    const float2* x2 = (const float2*)x;
    float z = 0.f, X0 = 0.f, X1 = 0.f;
    int j = 0;
    for (; j + 2 <= dc; j += 2) {
        unsigned w0 = csr_se[start + j];
        unsigned w1 = csr_se[start + j + 1];
        int s0 = w0 >> 15, s1 = w1 >> 15;
        float als0 = al_s1[4 * s0 + h];
        float als1 = al_s1[4 * s1 + h];
        float2 xs0 = x2[s0];
        float2 xs1 = x2[s1];
        float e0 = __expf(lrelu(als0 + ald + (float)(w0 & 32767u) * ceh));
        float e1 = __expf(lrelu(als1 + ald + (float)(w1 & 32767u) * ceh));
        z += e0 + e1;
        X0 += e0 * xs0.x + e1 * xs1.x;
        X1 += e0 * xs0.y + e1 * xs1.y;
    }
    if (j < dc) {
        unsigned w = csr_se[start + j];
        int s = w >> 15;
        float als = al_s1[4 * s + h];
        float2 xs = x2[s];
        float ex = __expf(lrelu(als + ald + (float)(w & 32767u) * ceh));
        z += ex;
        X0 += ex * xs.x;
        X1 += ex * xs.y;
    }
    float inv = 1.f / (z + 1e-16f);
    float xa0 = X0 * inv, xa1 = X1 * inv;
    XA[(size_t)4 * n + h] = make_float2(xa0, xa1);
    // al_s2/al_d2: reduce per-head partials over the 4-lane group
    float ps = xa0 * sS[h] + xa1 * sS[4 + h];
    float pd = xa0 * sS[8 + h] + xa1 * sS[12 + h];
    ps += __shfl_xor(ps, 1, 64); ps += __shfl_xor(ps, 2, 64);
    pd += __shfl_xor(pd, 1, 64); pd += __shfl_xor(pd, 2, 64);
    if (h == 0) {
        al_s2[n] = sS[16] + ps;
        al_d2[n] = sS[17] + pd;
    }
}

// ---------------- Layer-2 rank-8 aggregation -> packed fp16 (Y[8]) + w0 per node -----
// One lane per edge; 32B XA gathers (L2-resident 3.2MB table); exp once per edge.
// Output is the 9-dim compressed node state the edge regressor expands from.
__global__ __launch_bounds__(256) void msg2y_kernel(
    const unsigned* __restrict__ csr_se, const int* __restrict__ offs,
    const int* __restrict__ deg,
    const float* __restrict__ al_s2, const float* __restrict__ al_d2,
    const float* __restrict__ We2, const float* __restrict__ ae2,
    const float2* __restrict__ XA,
    uint4* __restrict__ Yh, float* __restrict__ w0n, int N) {
    __shared__ float sh[1];
    float ce2 = compute_ce2(We2, ae2, sh) * (1.f / 32767.f);
    int t = blockIdx.x * 256 + threadIdx.x;
    int n = t >> 2, q = t & 3;
    if (n >= N) return;
    int dc = deg[n];
    int start = offs[n] - dc;
    float ald = al_d2[n];
    const float4* xa4 = (const float4*)XA;   // node s -> xa4[2s], xa4[2s+1]
    float y0 = 0.f, y1 = 0.f, y2 = 0.f, y3 = 0.f;
    float y4 = 0.f, y5 = 0.f, y6 = 0.f, y7 = 0.f;
    float z = 0.f;
    int j = q;
    for (; j + 4 < dc; j += 8) {
        unsigned wA = csr_se[start + j];
        unsigned wB = csr_se[start + j + 4];
        int sA = wA >> 15, sB = wB >> 15;
        float alsA = al_s2[sA];
        float alsB = al_s2[sB];
        float4 a0 = xa4[(size_t)sA * 2];
        float4 a1 = xa4[(size_t)sA * 2 + 1];
        float4 b0 = xa4[(size_t)sB * 2];
        float4 b1 = xa4[(size_t)sB * 2 + 1];
        float exA = __expf(lrelu(alsA + ald + (float)(wA & 32767u) * ce2));
        float exB = __expf(lrelu(alsB + ald + (float)(wB & 32767u) * ce2));
        z += exA + exB;
        y0 += exA * a0.x + exB * b0.x;
        y1 += exA * a0.y + exB * b0.y;
        y2 += exA * a0.z + exB * b0.z;
        y3 += exA * a0.w + exB * b0.w;
        y4 += exA * a1.x + exB * b1.x;
        y5 += exA * a1.y + exB * b1.y;
        y6 += exA * a1.z + exB * b1.z;
        y7 += exA * a1.w + exB * b1.w;
    }
    if (j < dc) {
        unsigned w = csr_se[start + j];
        int s = w >> 15;
        float als = al_s2[s];
        float4 a0 = xa4[(size_t)s * 2];
        float4 a1 = xa4[(size_t)s * 2 + 1];
        float ex = __expf(lrelu(als + ald + (float)(w & 32767u) * ce2));
        z += ex;
        y0 += ex * a0.x; y1 += ex * a0.y; y2 += ex * a0.z; y3 += ex * a0.w;
        y4 += ex * a1.x; y5 += ex * a1.y; y6 += ex * a1.z; y7 += ex * a1.w;
    }
    // reduce 9 accumulators across the 4-lane group (xor butterfly -> all lanes full)
    y0 += __shfl_xor(y0, 1, 64); y0 += __shfl_xor(y0, 2, 64);
    y1 += __shfl_xor(y1, 1, 64); y1 += __shfl_xor(y1, 2, 64);
    y2 += __shfl_xor(y2, 1, 64); y2 += __shfl_xor(y2, 2, 64);
    y3 += __shfl_xor(y3, 1, 64); y3 += __shfl_xor(y3, 2, 64);
    y4 += __shfl_xor(y4, 1, 64); y4 += __shfl_xor(y4, 2, 64);
    y5 += __shfl_xor(y5, 1, 64); y5 += __shfl_xor(y5, 2, 64);
    y6 += __shfl_xor(y6, 1, 64); y6 += __shfl_xor(y6, 2, 64);
    y7 += __shfl_xor(y7, 1, 64); y7 += __shfl_xor(y7, 2, 64);
    z += __shfl_xor(z, 1, 64); z += __shfl_xor(z, 2, 64);
    if (q == 0) {
        float inv = 1.f / (z + 1e-16f);
        __half2 p0 = __floats2half2_rn(y0 * inv, y1 * inv);
        __half2 p1 = __floats2half2_rn(y2 * inv, y3 * inv);
        __half2 p2 = __floats2half2_rn(y4 * inv, y5 * inv);
        __half2 p3 = __floats2half2_rn(y6 * inv, y7 * inv);
        uint4 o;
        o.x = *(unsigned*)&p0; o.y = *(unsigned*)&p1;
        o.z = *(unsigned*)&p2; o.w = *(unsigned*)&p3;
        Yh[n] = o;
        w0n[n] = z * inv;   // ~1, or 0 for empty segments (kills cW term)
    }
}

// ---------------- Edge regressor: ONE THREAD PER EDGE, scalar-operand basis -----------
// The 9x64 basis (V) is wave-uniform: the unrolled k-loop reads compile-time offsets of
// V/br1/Wr2 -> s_loads feeding VALU as SGPR operands. Each thread owns one edge:
// 2 coalesced ei loads, 2x16B Yh gathers (1.6MB L2-resident), 2 w0 loads, then
// 64 dims x (9 FMA + max + FMA) with zero cross-lane redundancy.
__global__ __launch_bounds__(256) void edge_kernel(
    const int* __restrict__ ei,
    const uint4* __restrict__ Yh, const float* __restrict__ w0n,
    const float* __restrict__ V,
    const float* __restrict__ br1, const float* __restrict__ Wr2,
    const float* __restrict__ br2, float* __restrict__ out, int E) {
    int e = blockIdx.x * 256 + threadIdx.x;
    if (e >= E) return;
    int s = ei[e], d = ei[E + e];
    uint4 ys = Yh[s], yd = Yh[d];
    float w0 = w0n[s] + w0n[d];
    float fs[8], fd[8], tt[8];
    h8_to_f(ys, fs);
    h8_to_f(yd, fd);
#pragma unroll
    for (int i = 0; i < 8; ++i) tt[i] = fs[i] + fd[i];
    float acc = 0.f;
#pragma unroll
    for (int k = 0; k < 64; ++k) {
        float g = fmaf(w0, V[512 + k], fmaf(2.f, V[576 + k], br1[k]));
        g = fmaf(tt[0], V[k],       g);
        g = fmaf(tt[1], V[256 + k], g);
        g = fmaf(tt[2], V[64 + k],  g);
        g = fmaf(tt[3], V[320 + k], g);
        g = fmaf(tt[4], V[128 + k], g);
        g = fmaf(tt[5], V[384 + k], g);
        g = fmaf(tt[6], V[192 + k], g);
        g = fmaf(tt[7], V[448 + k], g);
        acc = fmaf(fmaxf(g, 0.f), Wr2[k], acc);
    }
    out[e] = acc + br2[0];
}

extern "C" void kernel_launch(void* const* d_in, const int* in_sizes, int n_in,
                              void* d_out, int out_size, void* d_ws, size_t ws_size,
                              hipStream_t stream) {
    const float* x    = (const float*)d_in[0];
    const int*   ei   = (const int*)d_in[1];
    const float* ea   = (const float*)d_in[2];
    const float* W1   = (const float*)d_in[3];
    const float* We1  = (const float*)d_in[4];
    const float* as1  = (const float*)d_in[5];
    const float* ad1  = (const float*)d_in[6];
    const float* ae1  = (const float*)d_in[7];
    const float* b1   = (const float*)d_in[8];
    const float* W2   = (const float*)d_in[9];
    const float* We2  = (const float*)d_in[10];
    const float* as2  = (const float*)d_in[11];
    const float* ad2  = (const float*)d_in[12];
    const float* ae2  = (const float*)d_in[13];
    const float* b2   = (const float*)d_in[14];
    const float* Wr1  = (const float*)d_in[15];
    const float* br1  = (const float*)d_in[16];
    const float* Wr2  = (const float*)d_in[17];
    const float* br2  = (const float*)d_in[18];
    float* out = (float*)d_out;

    const int N = in_sizes[0] / 2;
    const int E = in_sizes[2];
    const int nbuck = (N + 511) >> 9;
    const size_t capE = (size_t)nbuck * BCAP;   // fixed-capacity CSR address space

    // workspace layout
    float* ws = (float*)d_ws;
    float*    al_s1 = ws;                            // N*4
    float*    al_d1 = al_s1 + (size_t)N * 4;         // N*4
    float*    al_s2 = al_d1 + (size_t)N * 4;         // N
    float*    al_d2 = al_s2 + N;                     // N
    float2*   XA    = (float2*)((((uintptr_t)(al_d2 + N)) + 31) & ~(uintptr_t)31); // N*4 float2 (32B aligned)
    float*    V     = (float*)((((uintptr_t)(XA + (size_t)N * 4)) + 15) & ~(uintptr_t)15); // 658 (pad 704)
    int*      deg   = (int*)(V + 704);               // N
    int*      offs  = deg + N;                       // N
    int*      bucket_cur  = offs + N;                // 256
    uint4*    Yh    = (uint4*)((((uintptr_t)(bucket_cur + 256)) + 15) & ~(uintptr_t)15); // N uint4
    float*    w0n   = (float*)(Yh + N);              // N
    uint2*    ebm   = (uint2*)((((uintptr_t)(w0n + N)) + 15) & ~(uintptr_t)15); // capE uint2
    unsigned* csr_se = (unsigned*)(ebm + capE);      // capE

    const int nb = (N + 255) / 256;

    prep1_kernel<<<nb, 256, 0, stream>>>(x, W1, as1, ad1, W2, b1, Wr1, b2, as2, ad2,
                                         al_s1, al_d1, bucket_cur, V, N);
    binA_kernel<<<(E + TILE - 1) / TILE, 256, 0, stream>>>(ei, ea, bucket_cur, ebm,
                                                           E, nbuck);
    binB_kernel<<<nbuck, 256, 0, stream>>>(ebm, bucket_cur, deg, offs, csr_se, N);
    aggX_kernel<<<(4 * N + 255) / 256, 256, 0, stream>>>(csr_se, offs, deg,
                                                         al_s1, al_d1, x, We1, ae1, V,
                                                         XA, al_s2, al_d2, N);
    msg2y_kernel<<<(4 * N + 255) / 256, 256, 0, stream>>>(csr_se, offs, deg,
                                                          al_s2, al_d2, We2, ae2, XA,
                                                          Yh, w0n, N);
    edge_kernel<<<(E + 255) / 256, 256, 0, stream>>>(ei, Yh, w0n, V, br1, Wr2, br2,
                                                     out, E);
}

// Round 10
// 223.184 us; speedup vs baseline: 1.8136x; 1.0832x over previous
//
#include <hip/hip_runtime.h>
#include <hip/hip_bf16.h>
#include <hip/hip_fp16.h>

#define NEG_SLOPE 0.2f
#define NBUCK_MAX 256   // buckets of 512 nodes; 100k nodes -> 196 buckets
#define BCAP 12288      // fixed bucket capacity (mean 8163, sigma ~90 -> 45 sigma slack)
#define TILE 2048       // edges per binA block (8 per thread)

typedef float v2f __attribute__((ext_vector_type(2)));

__device__ __forceinline__ float lrelu(float v) { return v >= 0.f ? v : NEG_SLOPE * v; }

__device__ __forceinline__ float wave_sum(float v) {
    for (int o = 32; o; o >>= 1) v += __shfl_down(v, o, 64);
    return v;
}

__device__ __forceinline__ void h8_to_f(const uint4 v, float* f) {
    float2 a = __half22float2(*(const __half2*)&v.x);
    float2 b = __half22float2(*(const __half2*)&v.y);
    float2 c = __half22float2(*(const __half2*)&v.z);
    float2 d = __half22float2(*(const __half2*)&v.w);
    f[0] = a.x; f[1] = a.y; f[2] = b.x; f[3] = b.y;
    f[4] = c.x; f[5] = c.y; f[6] = d.x; f[7] = d.y;
}

// ce1[h] = dot(We1[h*64..], ae1[h*64..]) — wave h computes head h. 256 threads.
__device__ __forceinline__ void compute_ce1(const float* __restrict__ We1,
                                            const float* __restrict__ ae1,
                                            float* ce /*shared[4]*/) {
    int t = threadIdx.x;
    float p = wave_sum(We1[t] * ae1[t]);
    if ((t & 63) == 0) ce[t >> 6] = p;
    __syncthreads();
}

__device__ __forceinline__ float compute_ce2(const float* __restrict__ We2,
                                             const float* __restrict__ ae2,
                                             float* sh /*shared[1]*/) {
    int t = threadIdx.x;
    if (t < 64) {
        float p = wave_sum(We2[t] * ae2[t]);
        if (t == 0) sh[0] = p;
    }
    __syncthreads();
    return sh[0];
}

// ---------------- Layer-1 prep: node rec {al_s1[4],x0,x1}; al_d1; folded V -----------
// V layout (global): [0..255]=V0W, [256..511]=V1W, [512..575]=cW, [576..639]=cb2,
// [640..643]=V0.as2, [644..647]=V1.as2, [648..651]=V0.ad2, [652..655]=V1.ad2,
// [656]=c.as2, [657]=c.ad2, [672..735]=ccomb = 2*cb2 + br1
__global__ __launch_bounds__(256) void prep1_kernel(
    const float* __restrict__ x, const float* __restrict__ W1,
    const float* __restrict__ as1, const float* __restrict__ ad1,
    const float* __restrict__ W2, const float* __restrict__ b1,
    const float* __restrict__ Wr1, const float* __restrict__ b2,
    const float* __restrict__ as2, const float* __restrict__ ad2,
    const float* __restrict__ br1,
    float* __restrict__ rec, float* __restrict__ al_d1,
    int* __restrict__ bucket_cur, float* __restrict__ V, int N) {
    __shared__ float cs0[4], cs1[4], cd0[4], cd1[4];
    __shared__ float sV0[256], sV1[256], sc[64];
    int t = threadIdx.x;
    if (blockIdx.x == 0) bucket_cur[t] = t * BCAP;
    {
        float a = as1[t], d = ad1[t], u0 = W1[t], u1 = W1[256 + t];
        float p0 = wave_sum(u0 * a);
        float p1 = wave_sum(u1 * a);
        float q0 = wave_sum(u0 * d);
        float q1 = wave_sum(u1 * d);
        if ((t & 63) == 0) {
            int h = t >> 6;
            cs0[h] = p0; cs1[h] = p1; cd0[h] = q0; cd1[h] = q1;
        }
    }
    __syncthreads();
    int n = blockIdx.x * 256 + t;
    if (n < N) {
        float2 xs = ((const float2*)x)[n];
        float4 vs, vd;
        vs.x = xs.x * cs0[0] + xs.y * cs1[0];
        vs.y = xs.x * cs0[1] + xs.y * cs1[1];
        vs.z = xs.x * cs0[2] + xs.y * cs1[2];
        vs.w = xs.x * cs0[3] + xs.y * cs1[3];
        vd.x = xs.x * cd0[0] + xs.y * cd1[0];
        vd.y = xs.x * cd0[1] + xs.y * cd1[1];
        vd.z = xs.x * cd0[2] + xs.y * cd1[2];
        vd.w = xs.x * cd0[3] + xs.y * cd1[3];
        ((float4*)rec)[2 * n] = vs;                         // al_s1[0..3]
        ((float4*)rec)[2 * n + 1] = make_float4(xs.x, xs.y, 0.f, 0.f);
        ((float4*)al_d1)[n] = vd;
    }
    // block 0 epilogue: fold W1@W2 (=V0,V1), b1@W2 (=c), then push Wr1/as2/ad2 through
    if (blockIdx.x == 0) {
        int h = t >> 6, j = t & 63;
        float v0 = 0.f, v1 = 0.f;
        for (int k = 0; k < 64; ++k) {
            float w2 = W2[(h * 64 + k) * 64 + j];
            v0 += W1[h * 64 + k] * w2;
            v1 += W1[256 + h * 64 + k] * w2;
        }
        sV0[t] = v0;
        sV1[t] = v1;
        if (t < 64) {
            float c = 0.f;
            for (int i = 0; i < 256; ++i) c += b1[i] * W2[i * 64 + t];
            sc[t] = c;
        }
        __syncthreads();
        float v0w = 0.f, v1w = 0.f;
        for (int k = 0; k < 64; ++k) {
            float wr = Wr1[k * 64 + j];
            v0w += sV0[h * 64 + k] * wr;
            v1w += sV1[h * 64 + k] * wr;
        }
        V[t] = v0w;
        V[256 + t] = v1w;
        if (t < 64) {
            float cw = 0.f, cb = 0.f;
            for (int k = 0; k < 64; ++k) {
                float wr = Wr1[k * 64 + t];
                cw += sc[k] * wr;
                cb += b2[k] * wr;
            }
            V[512 + t] = cw;
            V[576 + t] = cb;
            V[672 + t] = 2.f * cb + br1[t];   // ccomb for the edge regressor
        }
        int lane = t & 63;
        float p0 = wave_sum(sV0[t] * as2[lane]);
        float p1 = wave_sum(sV1[t] * as2[lane]);
        float q0 = wave_sum(sV0[t] * ad2[lane]);
        float q1 = wave_sum(sV1[t] * ad2[lane]);
        if (lane == 0) {
            V[640 + h] = p0; V[644 + h] = p1; V[648 + h] = q0; V[652 + h] = q1;
        }
        if (t < 64) {
            float r0 = wave_sum(sc[t] * as2[t]);
            float r1 = wave_sum(sc[t] * ad2[t]);
            if (t == 0) { V[656] = r0; V[657] = r1; }
        }
    }
}

// ---------------- Pass A: tile-sorted binning (single pass over edges) ----------------
// One block per 2048-edge tile. Rank edges per bucket with LDS atomics, block-scan the
// bucket counts, reserve global space with <=196 block-level atomics (never per-edge),
// reorder records bucket-contiguously in LDS, then write out in position order.
// ebm.x = (src<<15) | ea15 ; ebm.y = (dst_local<<21) | eid
__global__ __launch_bounds__(256) void binA_kernel(
    const int* __restrict__ ei, const float* __restrict__ ea,
    int* __restrict__ bucket_cur, uint2* __restrict__ ebm, int E, int nbuck) {
    __shared__ int cnt[NBUCK_MAX];
    __shared__ int gbase[NBUCK_MAX];
    __shared__ int lofs[NBUCK_MAX];
    __shared__ int psum[NBUCK_MAX];
    __shared__ uint2 buf[TILE];
    __shared__ unsigned short bkt[TILE];
    int t = threadIdx.x;
    int e0 = blockIdx.x * TILE;
    int cntE = min(TILE, E - e0);
    for (int i = t; i < nbuck; i += 256) cnt[i] = 0;
    __syncthreads();
    uint2 rec[8];
    int rb[8], rr[8];
#pragma unroll
    for (int i = 0; i < 8; ++i) {
        int e = e0 + i * 256 + t;
        if (i * 256 + t < cntE) {
            int s = ei[e], d = ei[E + e];
            unsigned q = (unsigned)(ea[e] * 32767.f + 0.5f);
            q = min(q, 32767u);
            rec[i] = make_uint2((((unsigned)s) << 15) | q,
                                (unsigned)(((d & 511) << 21) | e));
            rb[i] = d >> 9;
            rr[i] = atomicAdd(&cnt[rb[i]], 1);
        } else {
            rb[i] = -1;
        }
    }
    __syncthreads();
    // exclusive scan of cnt over [0, nbuck) + global reservation (one atomic/bucket)
    int v = (t < nbuck) ? cnt[t] : 0;
    psum[t] = v;
    __syncthreads();
    for (int o = 1; o < 256; o <<= 1) {
        int a = (t >= o) ? psum[t - o] : 0;
        __syncthreads();
        psum[t] += a;
        __syncthreads();
    }
    if (t < nbuck) {
        lofs[t] = psum[t] - v;
        if (v) gbase[t] = atomicAdd(&bucket_cur[t], v);
    }
    __syncthreads();
    // scatter into LDS, bucket-contiguous
#pragma unroll
    for (int i = 0; i < 8; ++i) {
        if (rb[i] >= 0) {
            int p = lofs[rb[i]] + rr[i];
            buf[p] = rec[i];
            bkt[p] = (unsigned short)rb[i];
        }
    }
    __syncthreads();
    // write out: consecutive p -> consecutive slots within each bucket's run
    for (int p = t; p < cntE; p += 256) {
        int b = bkt[p];
        ebm[gbase[b] + (p - lofs[b])] = buf[p];
    }
}

// ---------------- Pass B: per bucket — LDS deg-histogram, local scan, exact scatter ----
__global__ __launch_bounds__(256) void binB_kernel(
    const uint2* __restrict__ ebm, const int* __restrict__ bucket_cur,
    int* __restrict__ deg, int* __restrict__ offs,
    unsigned* __restrict__ csr_se, int N) {
    __shared__ int lcnt[512];
    __shared__ int lofs[512];
    __shared__ int lcur[512];
    int b = blockIdx.x;
    int n0 = b << 9;
    int t = threadIdx.x;
    lcnt[t] = 0; lcnt[t + 256] = 0;
    __syncthreads();
    int bstart = b * BCAP;
    int bend = bucket_cur[b];      // post-binA == region fill end
    for (int p = bstart + t; p < bend; p += 256)
        atomicAdd(&lcnt[ebm[p].y >> 21], 1);
    __syncthreads();
    int a0 = lcnt[2 * t], a1 = lcnt[2 * t + 1];
    __shared__ int psum[256];
    psum[t] = a0 + a1;
    __syncthreads();
    for (int o = 1; o < 256; o <<= 1) {
        int a = (t >= o) ? psum[t - o] : 0;
        __syncthreads();
        psum[t] += a;
        __syncthreads();
    }
    int excl = psum[t] - (a0 + a1);
    lofs[2 * t] = excl;
    lofs[2 * t + 1] = excl + a0;
    lcur[2 * t] = bstart + excl;
    lcur[2 * t + 1] = bstart + excl + a0;
    __syncthreads();
    for (int i = t; i < 512; i += 256) {
        int n = n0 + i;
        if (n < N) {
            deg[n] = lcnt[i];
            offs[n] = bstart + lofs[i] + lcnt[i];   // segment END (fixed address space)
        }
    }
    for (int p = bstart + t; p < bend; p += 256) {
        uint2 m = ebm[p];
        int pos = atomicAdd(&lcur[m.y >> 21], 1);
        csr_se[pos] = m.x;
    }
}

// ---------------- Layer-1 aggregation + layer-2 logit scalars --------------------------
// Rank-2 softmax-weighted x aggregation per (node,head). Neighbor state is a packed
// 32B record {al_s1[4], x0, x1, pad} -> ONE cache line per gather (was 2 tables/lines).
__global__ __launch_bounds__(256) void aggX_kernel(
    const unsigned* __restrict__ csr_se, const int* __restrict__ offs,
    const int* __restrict__ deg,
    const float* __restrict__ rec, const float* __restrict__ al_d1,
    const float* __restrict__ We1, const float* __restrict__ ae1,
    const float* __restrict__ V,
    float2* __restrict__ XA, float* __restrict__ al_s2, float* __restrict__ al_d2,
    int N) {
    __shared__ float ce[4];
    __shared__ float sS[18];
    if (threadIdx.x < 18) sS[threadIdx.x] = V[640 + threadIdx.x];
    compute_ce1(We1, ae1, ce);
    int t = blockIdx.x * 256 + threadIdx.x;
    int n = t >> 2, h = t & 3;
    if (n >= N) return;
    int dc = deg[n];
    int start = offs[n] - dc;
    float ald = al_d1[4 * n + h];
    float ceh = ce[h] * (1.f / 32767.f);
    float z = 0.f, X0 = 0.f, X1 = 0.f;
    int j = 0;
    for (; j + 2 <= dc; j += 2) {
        unsigned w0 = csr_se[start + j];
        unsigned w1 = csr_se[start + j + 1];
        int s0 = w0 >> 15, s1 = w1 >> 15;
        const float* rb0 = rec + (size_t)8 * s0;
        const float* rb1 = rec + (size_t)8 * s1;
        float als0 = rb0[h];
        float als1 = rb1[h];
        float2 xs0 = *(const float2*)(rb0 + 4);
        float2 xs1 = *(const float2*)(rb1 + 4);
        float e0 = __expf(lrelu(als0 + ald + (float)(w0 & 32767u) * ceh));
        float e1 = __expf(lrelu(als1 + ald + (float)(w1 & 32767u) * ceh));
        z += e0 + e1;
        X0 += e0 * xs0.x + e1 * xs1.x;
        X1 += e0 * xs0.y + e1 * xs1.y;
    }
    if (j < dc) {
        unsigned w = csr_se[start + j];
        int s = w >> 15;
        const float* rb = rec + (size_t)8 * s;
        float als = rb[h];
        float2 xs = *(const float2*)(rb + 4);
        float ex = __expf(lrelu(als + ald + (float)(w & 32767u) * ceh));
        z += ex;
        X0 += ex * xs.x;
        X1 += ex * xs.y;
    }
    float inv = 1.f / (z + 1e-16f);
    float xa0 = X0 * inv, xa1 = X1 * inv;
    XA[(size_t)4 * n + h] = make_float2(xa0, xa1);
    // al_s2/al_d2: reduce per-head partials over the 4-lane group
    float ps = xa0 * sS[h] + xa1 * sS[4 + h];
    float pd = xa0 * sS[8 + h] + xa1 * sS[12 + h];
    ps += __shfl_xor(ps, 1, 64); ps += __shfl_xor(ps, 2, 64);
    pd += __shfl_xor(pd, 1, 64); pd += __shfl_xor(pd, 2, 64);
    if (h == 0) {
        al_s2[n] = sS[16] + ps;
        al_d2[n] = sS[17] + pd;
    }
}

// ---------------- Layer-2 rank-8 aggregation -> packed fp16 (Y[8]) + w0 per node -----
// One lane per edge; 32B XA gathers (L2-resident 3.2MB table); exp once per edge.
// al_s2[src] is recomputed IN-REGISTER from the gathered XA fragments (8 FMA) instead
// of a dependent 4B gather — one fewer random load stream per edge.
__global__ __launch_bounds__(256) void msg2y_kernel(
    const unsigned* __restrict__ csr_se, const int* __restrict__ offs,
    const int* __restrict__ deg,
    const float* __restrict__ al_d2,
    const float* __restrict__ We2, const float* __restrict__ ae2,
    const float* __restrict__ V,
    const float2* __restrict__ XA,
    uint4* __restrict__ Yh, float* __restrict__ w0n, int N) {
    __shared__ float sh[1];
    float ce2 = compute_ce2(We2, ae2, sh) * (1.f / 32767.f);
    float s16 = V[656];
    float ss0 = V[640], ss1 = V[641], ss2 = V[642], ss3 = V[643];
    float ss4 = V[644], ss5 = V[645], ss6 = V[646], ss7 = V[647];
    int t = blockIdx.x * 256 + threadIdx.x;
    int n = t >> 2, q = t & 3;
    if (n >= N) return;
    int dc = deg[n];
    int start = offs[n] - dc;
    float ald = al_d2[n];
    const float4* xa4 = (const float4*)XA;   // node s -> xa4[2s], xa4[2s+1]
    float y0 = 0.f, y1 = 0.f, y2 = 0.f, y3 = 0.f;
    float y4 = 0.f, y5 = 0.f, y6 = 0.f, y7 = 0.f;
    float z = 0.f;
    int j = q;
    for (; j + 4 < dc; j += 8) {
        unsigned wA = csr_se[start + j];
        unsigned wB = csr_se[start + j + 4];
        int sA = wA >> 15, sB = wB >> 15;
        float4 a0 = xa4[(size_t)sA * 2];
        float4 a1 = xa4[(size_t)sA * 2 + 1];
        float4 b0 = xa4[(size_t)sB * 2];
        float4 b1 = xa4[(size_t)sB * 2 + 1];
        float alsA = s16 + a0.x * ss0 + a0.y * ss4 + a0.z * ss1 + a0.w * ss5
                         + a1.x * ss2 + a1.y * ss6 + a1.z * ss3 + a1.w * ss7;
        float alsB = s16 + b0.x * ss0 + b0.y * ss4 + b0.z * ss1 + b0.w * ss5
                         + b1.x * ss2 + b1.y * ss6 + b1.z * ss3 + b1.w * ss7;
        float exA = __expf(lrelu(alsA + ald + (float)(wA & 32767u) * ce2));
        float exB = __expf(lrelu(alsB + ald + (float)(wB & 32767u) * ce2));
        z += exA + exB;
        y0 += exA * a0.x + exB * b0.x;
        y1 += exA * a0.y + exB * b0.y;
        y2 += exA * a0.z + exB * b0.z;
        y3 += exA * a0.w + exB * b0.w;
        y4 += exA * a1.x + exB * b1.x;
        y5 += exA * a1.y + exB * b1.y;
        y6 += exA * a1.z + exB * b1.z;
        y7 += exA * a1.w + exB * b1.w;
    }
    if (j < dc) {
        unsigned w = csr_se[start + j];
        int s = w >> 15;
        float4 a0 = xa4[(size_t)s * 2];
        float4 a1 = xa4[(size_t)s * 2 + 1];
        float als = s16 + a0.x * ss0 + a0.y * ss4 + a0.z * ss1 + a0.w * ss5
                        + a1.x * ss2 + a1.y * ss6 + a1.z * ss3 + a1.w * ss7;
        float ex = __expf(lrelu(als + ald + (float)(w & 32767u) * ce2));
        z += ex;
        y0 += ex * a0.x; y1 += ex * a0.y; y2 += ex * a0.z; y3 += ex * a0.w;
        y4 += ex * a1.x; y5 += ex * a1.y; y6 += ex * a1.z; y7 += ex * a1.w;
    }
    // reduce 9 accumulators across the 4-lane group (xor butterfly -> all lanes full)
    y0 += __shfl_xor(y0, 1, 64); y0 += __shfl_xor(y0, 2, 64);
    y1 += __shfl_xor(y1, 1, 64); y1 += __shfl_xor(y1, 2, 64);
    y2 += __shfl_xor(y2, 1, 64); y2 += __shfl_xor(y2, 2, 64);
    y3 += __shfl_xor(y3, 1, 64); y3 += __shfl_xor(y3, 2, 64);
    y4 += __shfl_xor(y4, 1, 64); y4 += __shfl_xor(y4, 2, 64);
    y5 += __shfl_xor(y5, 1, 64); y5 += __shfl_xor(y5, 2, 64);
    y6 += __shfl_xor(y6, 1, 64); y6 += __shfl_xor(y6, 2, 64);
    y7 += __shfl_xor(y7, 1, 64); y7 += __shfl_xor(y7, 2, 64);
    z += __shfl_xor(z, 1, 64); z += __shfl_xor(z, 2, 64);
    if (q == 0) {
        float inv = 1.f / (z + 1e-16f);
        __half2 p0 = __floats2half2_rn(y0 * inv, y1 * inv);
        __half2 p1 = __floats2half2_rn(y2 * inv, y3 * inv);
        __half2 p2 = __floats2half2_rn(y4 * inv, y5 * inv);
        __half2 p3 = __floats2half2_rn(y6 * inv, y7 * inv);
        uint4 o;
        o.x = *(unsigned*)&p0; o.y = *(unsigned*)&p1;
        o.z = *(unsigned*)&p2; o.w = *(unsigned*)&p3;
        Yh[n] = o;
        w0n[n] = z * inv;   // ~1, or 0 for empty segments (kills cW term)
    }
}

// ---------------- Edge regressor: thread/edge, scalar basis, PACKED fp32 math ---------
// k-loop over dim PAIRS with ext_vector float2 ops -> v_pk_fma_f32 (2 FMA/instr).
// Basis pairs are wave-uniform 8B loads (s_load_dwordx2, one 64-bit scalar operand).
// ccomb = 2*cb2 + br1 precomputed in V[672..735] so each op keeps 1 scalar operand.
// ~384 wave-instr/edge vs ~740 scalar. Falls back to scalar codegen (same as R9) if
// ISel declines VOP3P — zero-risk floor.
__global__ __launch_bounds__(256) void edge_kernel(
    const int* __restrict__ ei,
    const uint4* __restrict__ Yh, const float* __restrict__ w0n,
    const float* __restrict__ V,
    const float* __restrict__ Wr2,
    const float* __restrict__ br2, float* __restrict__ out, int E) {
    int e = blockIdx.x * 256 + threadIdx.x;
    if (e >= E) return;
    int s = ei[e], d = ei[E + e];
    uint4 ys = Yh[s], yd = Yh[d];
    float w0 = w0n[s] + w0n[d];
    float fs[8], fd[8], tt[8];
    h8_to_f(ys, fs);
    h8_to_f(yd, fd);
#pragma unroll
    for (int i = 0; i < 8; ++i) tt[i] = fs[i] + fd[i];
    v2f acc = {0.f, 0.f};
    v2f w0v = {w0, w0};
#pragma unroll
    for (int k = 0; k < 64; k += 2) {
        v2f g = w0v * (*(const v2f*)(V + 512 + k));
        g += *(const v2f*)(V + 672 + k);
        g += (v2f){tt[0], tt[0]} * (*(const v2f*)(V + k));
        g += (v2f){tt[1], tt[1]} * (*(const v2f*)(V + 256 + k));
        g += (v2f){tt[2], tt[2]} * (*(const v2f*)(V + 64 + k));
        g += (v2f){tt[3], tt[3]} * (*(const v2f*)(V + 320 + k));
        g += (v2f){tt[4], tt[4]} * (*(const v2f*)(V + 128 + k));
        g += (v2f){tt[5], tt[5]} * (*(const v2f*)(V + 384 + k));
        g += (v2f){tt[6], tt[6]} * (*(const v2f*)(V + 192 + k));
        g += (v2f){tt[7], tt[7]} * (*(const v2f*)(V + 448 + k));
        g = __builtin_elementwise_max(g, (v2f){0.f, 0.f});
        acc += g * (*(const v2f*)(Wr2 + k));
    }
    out[e] = acc.x + acc.y + br2[0];
}

extern "C" void kernel_launch(void* const* d_in, const int* in_sizes, int n_in,
                              void* d_out, int out_size, void* d_ws, size_t ws_size,
                              hipStream_t stream) {
    const float* x    = (const float*)d_in[0];
    const int*   ei   = (const int*)d_in[1];
    const float* ea   = (const float*)d_in[2];
    const float* W1   = (const float*)d_in[3];
    const float* We1  = (const float*)d_in[4];
    const float* as1  = (const float*)d_in[5];
    const float* ad1  = (const float*)d_in[6];
    const float* ae1  = (const float*)d_in[7];
    const float* b1   = (const float*)d_in[8];
    const float* W2   = (const float*)d_in[9];
    const float* We2  = (const float*)d_in[10];
    const float* as2  = (const float*)d_in[11];
    const float* ad2  = (const float*)d_in[12];
    const float* ae2  = (const float*)d_in[13];
    const float* b2   = (const float*)d_in[14];
    const float* Wr1  = (const float*)d_in[15];
    const float* br1  = (const float*)d_in[16];
    const float* Wr2  = (const float*)d_in[17];
    const float* br2  = (const float*)d_in[18];
    float* out = (float*)d_out;

    const int N = in_sizes[0] / 2;
    const int E = in_sizes[2];
    const int nbuck = (N + 511) >> 9;
    const size_t capE = (size_t)nbuck * BCAP;   // fixed-capacity CSR address space

    // workspace layout
    float* ws = (float*)d_ws;
    float*    rec   = ws;                            // N*8 {al_s1[4], x0, x1, pad, pad}
    float*    al_d1 = rec + (size_t)N * 8;           // N*4
    float*    al_s2 = al_d1 + (size_t)N * 4;         // N
    float*    al_d2 = al_s2 + N;                     // N
    float2*   XA    = (float2*)((((uintptr_t)(al_d2 + N)) + 31) & ~(uintptr_t)31); // N*4 float2 (32B aligned)
    float*    V     = (float*)((((uintptr_t)(XA + (size_t)N * 4)) + 15) & ~(uintptr_t)15); // 736 (pad 768)
    int*      deg   = (int*)(V + 768);               // N
    int*      offs  = deg + N;                       // N
    int*      bucket_cur  = offs + N;                // 256
    uint4*    Yh    = (uint4*)((((uintptr_t)(bucket_cur + 256)) + 15) & ~(uintptr_t)15); // N uint4
    float*    w0n   = (float*)(Yh + N);              // N
    uint2*    ebm   = (uint2*)((((uintptr_t)(w0n + N)) + 15) & ~(uintptr_t)15); // capE uint2
    unsigned* csr_se = (unsigned*)(ebm + capE);      // capE

    const int nb = (N + 255) / 256;

    prep1_kernel<<<nb, 256, 0, stream>>>(x, W1, as1, ad1, W2, b1, Wr1, b2, as2, ad2,
                                         br1, rec, al_d1, bucket_cur, V, N);
    binA_kernel<<<(E + TILE - 1) / TILE, 256, 0, stream>>>(ei, ea, bucket_cur, ebm,
                                                           E, nbuck);
    binB_kernel<<<nbuck, 256, 0, stream>>>(ebm, bucket_cur, deg, offs, csr_se, N);
    aggX_kernel<<<(4 * N + 255) / 256, 256, 0, stream>>>(csr_se, offs, deg,
                                                         rec, al_d1, We1, ae1, V,
                                                         XA, al_s2, al_d2, N);
    msg2y_kernel<<<(4 * N + 255) / 256, 256, 0, stream>>>(csr_se, offs, deg,
                                                          al_d2, We2, ae2, V, XA,
                                                          Yh, w0n, N);
    edge_kernel<<<(E + 255) / 256, 256, 0, stream>>>(ei, Yh, w0n, V, Wr2, br2,
                                                     out, E);
}